// Round 2
// 361.064 us; speedup vs baseline: 1.1128x; 1.1128x over previous
//
#include <hip/hip_runtime.h>

// Neurcomp / SIREN MLP inference — round 8: swapped-operand MFMA, all transposes
// via one LDS b128 round-trip mechanism.
// r7 post-mortem: permlane32/16_swap-based transpose produced garbage (absmax
// 0.21); those are gfx950-new instrs with unverified pair/row semantics. Every
// other path (s1 LDS staging, F0, bias-rows, head) hand-simulated correct.
// Fix: h -> B-fragment transpose now uses the SAME swizzled b128 LDS pattern
// as the s1 staging (write f4v at block (4nt+q)^lnk of the point-row, read
// back two b128 per kc, split-on-read). Arithmetic (truncation hi/lo split,
// term order) kept bit-identical to the verified r6 kernel.
// Layouts (learn_hip m89/m120, r6-verified): A[m=lane&15][k=(lane>>4)*8+j],
// B[k=(lane>>4)*8+j][n=lane&15], D row(=A's m)=(lane>>4)*4+reg, col(=B's n)=lane&15.
// Here A = weights (prep layout unchanged: A-frag of W == old B-frag of W),
// B = activations, so D has feature at row, point at col=ln.

typedef unsigned int u32;
typedef short s8v __attribute__((ext_vector_type(8)));   // 8 bf16 (bits)
typedef float f4v __attribute__((ext_vector_type(4)));
typedef u32   u4v __attribute__((ext_vector_type(4)));

constexpr float OMEGA = 30.0f;
constexpr int HID = 128, NRES = 7, BT = 256;
constexpr int WROW = 136;              // dwords per LDS row: 32 b128-blocks + 2 pad
constexpr int WAVE_LDS = 32 * WROW;    // 4352 dwords per wave
constexpr int FRAG_ELEMS = 14 * 16384; // bf16 elems per hi/lo ws array

__device__ __forceinline__ float sin_om(float z) {
    float r = z * (OMEGA * 0.15915494309189535f);
    r = r - floorf(r);
    return __builtin_amdgcn_sinf(r);
}

__device__ __forceinline__ f4v mfma16(s8v a, s8v b, f4v c) {
    return __builtin_amdgcn_mfma_f32_16x16x32_bf16(a, b, c, 0, 0, 0);
}

__device__ __forceinline__ u32 fu(float f) { return __builtin_bit_cast(u32, f); }
__device__ __forceinline__ float andf(float f) {
    return __builtin_bit_cast(float, __builtin_bit_cast(u32, f) & 0xffff0000u);
}

// 8 fp32 (frag elem order j=0..7) -> hi s8v + lo s8v (truncation split, same
// math as r6's packf/FRAGS path: hi = top16, lo = top16 of (f - hi)).
// v_perm sel 0x07060302: D = {a.hi16 (top), b.hi16 (low)}.
#define PK8(e0,e1,e2,e3,e4,e5,e6,e7, FH_, FL_) { \
    u4v h_, l_; \
    h_.x = __builtin_amdgcn_perm(fu(e1), fu(e0), 0x07060302u); \
    h_.y = __builtin_amdgcn_perm(fu(e3), fu(e2), 0x07060302u); \
    h_.z = __builtin_amdgcn_perm(fu(e5), fu(e4), 0x07060302u); \
    h_.w = __builtin_amdgcn_perm(fu(e7), fu(e6), 0x07060302u); \
    float L0_ = e0 - andf(e0), L1_ = e1 - andf(e1); \
    float L2_ = e2 - andf(e2), L3_ = e3 - andf(e3); \
    float L4_ = e4 - andf(e4), L5_ = e5 - andf(e5); \
    float L6_ = e6 - andf(e6), L7_ = e7 - andf(e7); \
    l_.x = __builtin_amdgcn_perm(fu(L1_), fu(L0_), 0x07060302u); \
    l_.y = __builtin_amdgcn_perm(fu(L3_), fu(L2_), 0x07060302u); \
    l_.z = __builtin_amdgcn_perm(fu(L5_), fu(L4_), 0x07060302u); \
    l_.w = __builtin_amdgcn_perm(fu(L7_), fu(L6_), 0x07060302u); \
    FH_ = __builtin_bit_cast(s8v, h_); FL_ = __builtin_bit_cast(s8v, l_); }

// h (D-layout regs, feature 16nt+4q+reg at point-row) -> LDS, b128 swizzled.
// Block b holds features 4b+{0..3} of this row (same convention as s1 staging).
#define WH(mt,nt) { \
    f4v hv_; hv_.x = H_##mt##_##nt##_0; hv_.y = H_##mt##_##nt##_1; \
    hv_.z = H_##mt##_##nt##_2; hv_.w = H_##mt##_##nt##_3; \
    *(f4v*)&buf[(mt ? rowbase1 : rowbase0) + ((((nt)*4 + q) ^ lnk) << 2)] = hv_; }

// LDS (fp32, XOR-swizzled b128 blocks) -> B-fragments, split-on-read.
// Frag elem j at lane (q,ln): value[feature 32kc+8q+j][point row].
#define RS(mt,kc) { \
    const int rb_ = mt ? rowbase1 : rowbase0; \
    f4v u_ = *(const f4v*)&buf[rb_ + ((((kc)*8 + q*2    ) ^ lnk) << 2)]; \
    f4v v_ = *(const f4v*)&buf[rb_ + ((((kc)*8 + q*2 + 1) ^ lnk) << 2)]; \
    PK8(u_.x, u_.y, u_.z, u_.w, v_.x, v_.y, v_.z, v_.w, FH##mt##kc, FL##mt##kc) }

// 24 MFMAs for one output n-tile t: A = weight frags (hi/lo), B = act frags.
// Term order per kc matches r6 exactly: Wh*Hh, Wh*Hl, Wl*Hh.
#define MMBLK(fbv) \
    u4v g0_ = whi[fbv], g1_ = whi[(fbv)+64], g2_ = whi[(fbv)+128], g3_ = whi[(fbv)+192]; \
    u4v r0_ = wlo[fbv], r1_ = wlo[(fbv)+64], r2_ = wlo[(fbv)+128], r3_ = wlo[(fbv)+192]; \
    s8v bh_, bl_; \
    bh_ = __builtin_bit_cast(s8v, g0_); bl_ = __builtin_bit_cast(s8v, r0_); \
    c0 = mfma16(bh_, FH00, c0); c0 = mfma16(bh_, FL00, c0); c0 = mfma16(bl_, FH00, c0); \
    c1 = mfma16(bh_, FH10, c1); c1 = mfma16(bh_, FL10, c1); c1 = mfma16(bl_, FH10, c1); \
    bh_ = __builtin_bit_cast(s8v, g1_); bl_ = __builtin_bit_cast(s8v, r1_); \
    c0 = mfma16(bh_, FH01, c0); c0 = mfma16(bh_, FL01, c0); c0 = mfma16(bl_, FH01, c0); \
    c1 = mfma16(bh_, FH11, c1); c1 = mfma16(bh_, FL11, c1); c1 = mfma16(bl_, FH11, c1); \
    bh_ = __builtin_bit_cast(s8v, g2_); bl_ = __builtin_bit_cast(s8v, r2_); \
    c0 = mfma16(bh_, FH02, c0); c0 = mfma16(bh_, FL02, c0); c0 = mfma16(bl_, FH02, c0); \
    c1 = mfma16(bh_, FH12, c1); c1 = mfma16(bh_, FL12, c1); c1 = mfma16(bl_, FH12, c1); \
    bh_ = __builtin_bit_cast(s8v, g3_); bl_ = __builtin_bit_cast(s8v, r3_); \
    c0 = mfma16(bh_, FH03, c0); c0 = mfma16(bh_, FL03, c0); c0 = mfma16(bl_, FH03, c0); \
    c1 = mfma16(bh_, FH13, c1); c1 = mfma16(bh_, FL13, c1); c1 = mfma16(bl_, FH13, c1);

// ---- repetition lists ----
#define LNT8(M) M(0) M(1) M(2) M(3) M(4) M(5) M(6) M(7)
#define LW16(M) M(0,0) M(0,1) M(0,2) M(0,3) M(0,4) M(0,5) M(0,6) M(0,7) \
                M(1,0) M(1,1) M(1,2) M(1,3) M(1,4) M(1,5) M(1,6) M(1,7)
#define LH64(M) \
  M(0,0,0) M(0,0,1) M(0,0,2) M(0,0,3) M(0,1,0) M(0,1,1) M(0,1,2) M(0,1,3) \
  M(0,2,0) M(0,2,1) M(0,2,2) M(0,2,3) M(0,3,0) M(0,3,1) M(0,3,2) M(0,3,3) \
  M(0,4,0) M(0,4,1) M(0,4,2) M(0,4,3) M(0,5,0) M(0,5,1) M(0,5,2) M(0,5,3) \
  M(0,6,0) M(0,6,1) M(0,6,2) M(0,6,3) M(0,7,0) M(0,7,1) M(0,7,2) M(0,7,3) \
  M(1,0,0) M(1,0,1) M(1,0,2) M(1,0,3) M(1,1,0) M(1,1,1) M(1,1,2) M(1,1,3) \
  M(1,2,0) M(1,2,1) M(1,2,2) M(1,2,3) M(1,3,0) M(1,3,1) M(1,3,2) M(1,3,3) \
  M(1,4,0) M(1,4,1) M(1,4,2) M(1,4,3) M(1,5,0) M(1,5,1) M(1,5,2) M(1,5,3) \
  M(1,6,0) M(1,6,1) M(1,6,2) M(1,6,3) M(1,7,0) M(1,7,1) M(1,7,2) M(1,7,3)

#define DH(mt,nt,reg) float H_##mt##_##nt##_##reg;

// first layer: H[mt][nt][reg] = sin(omega*(w0[f]·x + b0[f])), f = 16*nt+4*q+reg,
// point p = base + mt*16 + ln. w0 rows r=0..3 packed in 3 f4v (12 floats).
#define F0(nt) { \
    f4v wa_ = *(const f4v*)(w0p + nt*48 + q*12); \
    f4v wb_ = *(const f4v*)(w0p + nt*48 + q*12 + 4); \
    f4v wc_ = *(const f4v*)(w0p + nt*48 + q*12 + 8); \
    f4v bb_ = *(const f4v*)(b0p + nt*16 + q4); \
    H_0_##nt##_0 = sin_om(fmaf(wa_.x, X0, fmaf(wa_.y, Y0, fmaf(wa_.z, Z0, bb_.x)))); \
    H_0_##nt##_1 = sin_om(fmaf(wa_.w, X0, fmaf(wb_.x, Y0, fmaf(wb_.y, Z0, bb_.y)))); \
    H_0_##nt##_2 = sin_om(fmaf(wb_.z, X0, fmaf(wb_.w, Y0, fmaf(wc_.x, Z0, bb_.z)))); \
    H_0_##nt##_3 = sin_om(fmaf(wc_.y, X0, fmaf(wc_.z, Y0, fmaf(wc_.w, Z0, bb_.w)))); \
    H_1_##nt##_0 = sin_om(fmaf(wa_.x, X1, fmaf(wa_.y, Y1, fmaf(wa_.z, Z1, bb_.x)))); \
    H_1_##nt##_1 = sin_om(fmaf(wa_.w, X1, fmaf(wb_.x, Y1, fmaf(wb_.y, Z1, bb_.y)))); \
    H_1_##nt##_2 = sin_om(fmaf(wb_.z, X1, fmaf(wb_.w, Y1, fmaf(wc_.x, Z1, bb_.z)))); \
    H_1_##nt##_3 = sin_om(fmaf(wc_.y, X1, fmaf(wc_.z, Y1, fmaf(wc_.w, Z1, bb_.w)))); }

// mm2 + epilogue (h += s2; last-layer 0.5 folded into the head)
#define ST(t) { \
    const int fb_ = fb2 + t*256; \
    f4v c0 = *(const f4v*)(B2l + t*16 + q4); f4v c1 = c0; \
    MMBLK(fb_) \
    H_0_##t##_0 += sin_om(c0.x); H_0_##t##_1 += sin_om(c0.y); \
    H_0_##t##_2 += sin_om(c0.z); H_0_##t##_3 += sin_om(c0.w); \
    H_1_##t##_0 += sin_om(c1.x); H_1_##t##_1 += sin_om(c1.y); \
    H_1_##t##_2 += sin_om(c1.z); H_1_##t##_3 += sin_om(c1.w); }

// final head partials
#define HF(nt) { f4v wf_ = *(const f4v*)(wfp + nt*16 + q4); \
    P0 = fmaf(wf_.x, H_0_##nt##_0, fmaf(wf_.y, H_0_##nt##_1, \
         fmaf(wf_.z, H_0_##nt##_2, fmaf(wf_.w, H_0_##nt##_3, P0)))); \
    P1 = fmaf(wf_.x, H_1_##nt##_0, fmaf(wf_.y, H_1_##nt##_1, \
         fmaf(wf_.z, H_1_##nt##_2, fmaf(wf_.w, H_1_##nt##_3, P1)))); }

// ---- weight prep: fp32 W -> hi/lo bf16 fragments in d_ws (UNCHANGED from r6;
// the same element layout serves as the A-operand fragment of W) ----
__global__ void prep_kernel(const float* __restrict__ rw1,
                            const float* __restrict__ rw2,
                            unsigned short* __restrict__ wsHi,
                            unsigned short* __restrict__ wsLo) {
    int id = blockIdx.x * 256 + threadIdx.x;      // 0 .. 28671
    int lane = id & 63, kc = (id >> 6) & 3, t = (id >> 8) & 7, L = id >> 11;
    int i = L >> 1;
    bool isW1 = ((L & 1) == 0);
    const float* W = (isW1 ? rw1 : rw2) + i * HID * HID;
    float sc = (isW1 && i > 0) ? 0.5f : 1.0f;     // fold wgt1 (ave_first)
    int n = t * 16 + (lane & 15);                  // output feature
    int k0 = kc * 32 + (lane >> 4) * 8;            // input feature base
    const float* src = W + n * HID + k0;           // W[n][k0..k0+7]
    int off = id * 8;
    for (int j = 0; j < 8; ++j) {
        float w = src[j] * sc;
        u32 b = __builtin_bit_cast(u32, w);
        u32 hb = b & 0xffff0000u;
        float lo = w - __builtin_bit_cast(float, hb);
        wsHi[off + j] = (unsigned short)(b >> 16);
        wsLo[off + j] = (unsigned short)(__builtin_bit_cast(u32, lo) >> 16);
    }
}

__global__ void __launch_bounds__(BT)
__attribute__((amdgpu_waves_per_eu(2, 2)))
siren_mfma(const float* __restrict__ x,
           const float* __restrict__ w0p, const float* __restrict__ b0p,
           const float* __restrict__ b1p, const float* __restrict__ b2p,
           const float* __restrict__ wfp, const float* __restrict__ bfp,
           const u4v* __restrict__ whi, const u4v* __restrict__ wlo,
           float* __restrict__ out, int NP)
{
    __shared__ float buf[4 * WAVE_LDS];            // 69632 B, wave-private staging

    const int tid = threadIdx.x;
    const int wv = tid >> 6, lane = tid & 63;
    const int ln = lane & 15, q = lane >> 4;
    const int q4 = q * 4;
    const int lnk = ln & 7;                        // LDS XOR-swizzle key (per row)
    const int rowbase0 = wv * WAVE_LDS + ln * WROW;        // mt0 row (point = ln)
    const int rowbase1 = rowbase0 + 16 * WROW;             // mt1 row (point = 16+ln)
    const int base_pt = blockIdx.x * 128 + wv * 32;

    // ---- first SineLayer, feature-major H: H[mt][nt][reg] = h[16nt+q4+reg][mt*16+ln]
    LH64(DH)
    {
        int p0_ = base_pt + ln;      int i0_ = p0_ < NP ? p0_ : NP - 1;
        int p1_ = base_pt + 16 + ln; int i1_ = p1_ < NP ? p1_ : NP - 1;
        float X0 = x[3*i0_], Y0 = x[3*i0_+1], Z0 = x[3*i0_+2];
        float X1 = x[3*i1_], Y1 = x[3*i1_+1], Z1 = x[3*i1_+2];
        LNT8(F0)
    }

    // activation B-fragments (hi/lo) for 2 point-tiles x 4 k-chunks
    s8v FH00, FH01, FH02, FH03, FH10, FH11, FH12, FH13;
    s8v FL00, FL01, FL02, FL03, FL10, FL11, FL12, FL13;

    for (int i = 0; i < NRES; ++i) {
        const int L1 = 2 * i, L2 = 2 * i + 1;
        const float* __restrict__ B1l = b1p + i * HID;
        const float* __restrict__ B2l = b2p + i * HID;

        // h (D-layout) -> LDS -> B-fragments (swizzled b128 round-trip)
        LW16(WH)
        RS(0,0) RS(0,1) RS(0,2) RS(0,3)
        RS(1,0) RS(1,1) RS(1,2) RS(1,3)

        // ---- matmul1 -> s1 (sine applied), staged fp32 to LDS (b128, swizzled)
        const int fb1 = L1 * 2048 + lane;
        #pragma unroll
        for (int t = 0; t < 8; ++t) {
            const int fb_ = fb1 + t * 256;
            f4v c0 = *(const f4v*)(B1l + t*16 + q4); f4v c1 = c0;
            MMBLK(fb_)
            f4v s0v, s1v;
            s0v.x = sin_om(c0.x); s0v.y = sin_om(c0.y);
            s0v.z = sin_om(c0.z); s0v.w = sin_om(c0.w);
            s1v.x = sin_om(c1.x); s1v.y = sin_om(c1.y);
            s1v.z = sin_om(c1.z); s1v.w = sin_om(c1.w);
            const int bo_ = ((t*4 + q) ^ lnk) << 2;        // b128 block, swizzled
            *(f4v*)&buf[rowbase0 + bo_] = s0v;
            *(f4v*)&buf[rowbase1 + bo_] = s1v;
        }

        // s1 -> fragments (split-on-read)
        RS(0,0) RS(0,1) RS(0,2) RS(0,3)
        RS(1,0) RS(1,1) RS(1,2) RS(1,3)

        // ---- matmul2 -> s2; epilogue h += s2 (last-layer 0.5 folded into head)
        const int fb2 = L2 * 2048 + lane;
        LNT8(ST)
    }

    // ---- final linear head: partial over this lane's 32 features, reduce over q
    float P0 = 0.f, P1 = 0.f;
    LNT8(HF)
    P0 += __shfl_xor(P0, 16); P0 += __shfl_xor(P0, 32);
    P1 += __shfl_xor(P1, 16); P1 += __shfl_xor(P1, 32);
    const float bf0 = bfp[0];
    if (q == 0) {
        int p0_ = base_pt + ln;
        if (p0_ < NP) out[p0_] = fmaf(P0, 0.5f, bf0);      // 0.5 = last-layer wgt2
        int p1_ = base_pt + 16 + ln;
        if (p1_ < NP) out[p1_] = fmaf(P1, 0.5f, bf0);
    }
}

extern "C" void kernel_launch(void* const* d_in, const int* in_sizes, int n_in,
                              void* d_out, int out_size, void* d_ws, size_t ws_size,
                              hipStream_t stream) {
    const float* x   = (const float*)d_in[0];
    const float* w0  = (const float*)d_in[1];
    const float* b0  = (const float*)d_in[2];
    const float* rw1 = (const float*)d_in[3];
    const float* rb1 = (const float*)d_in[4];
    const float* rw2 = (const float*)d_in[5];
    const float* rb2 = (const float*)d_in[6];
    const float* wf  = (const float*)d_in[7];
    const float* bf  = (const float*)d_in[8];
    float* out = (float*)d_out;

    unsigned short* wsHi = (unsigned short*)d_ws;          // needs 917504 B
    unsigned short* wsLo = wsHi + FRAG_ELEMS;

    const int n = in_sizes[0] / 3;                          // 200000
    prep_kernel<<<112, 256, 0, stream>>>(rw1, rw2, wsHi, wsLo);
    const int grid = (n + 127) / 128;
    siren_mfma<<<grid, BT, 0, stream>>>(x, w0, b0, rb1, rb2, wf, bf,
                                        (const u4v*)wsHi, (const u4v*)wsLo,
                                        out, n);
}